// Round 1
// baseline (1742.352 us; speedup 1.0000x reference)
//
#include <hip/hip_runtime.h>
#include <hip/hip_bf16.h>
#include <cmath>

// Problem: b=4, s=4096, d=1024, h=16, dh=64.  TOK = b*s = 16384.
// out = ((elu(x@wq^T)+1) applied linear-attn with kf,v) @ wo^T + bo
//
// ws layout (floats):
//   kf   : TOK*1024
//   v    : TOK*1024
//   qf   : TOK*1024   (attn output overwrites in-place)
//   kvp  : SPLIT*64*4096   (kv partials)
//   ksp  : SPLIT*64*64     (k_sum partials)
//   kv   : 64*4096
//   ksum : 64*64

#define TOK   16384
#define DMODEL 1024
#define NHEAD 16
#define DH    64
#define SPLIT 8

// ---------------- GEMM: C[M,N] = A[M,K] @ B[N,K]^T, fp32 ----------------
// ACT: 0 = none, 1 = elu(x)+1, 2 = +bias
#define BM 128
#define BN 128
#define BK 16

template<int ACT>
__global__ __launch_bounds__(256) void gemm_bt_k(
    const float* __restrict__ A, const float* __restrict__ Bm,
    const float* __restrict__ bias, float* __restrict__ C,
    int M, int N, int K)
{
    __shared__ float As[BK][BM + 4];
    __shared__ float Bs[BK][BN + 4];
    const int tid = threadIdx.x;
    const int m0 = blockIdx.y * BM;
    const int n0 = blockIdx.x * BN;
    const int tx = tid & 15, ty = tid >> 4;

    float acc[8][8];
#pragma unroll
    for (int i = 0; i < 8; ++i)
#pragma unroll
        for (int j = 0; j < 8; ++j) acc[i][j] = 0.f;

    for (int k0 = 0; k0 < K; k0 += BK) {
        __syncthreads();
#pragma unroll
        for (int it = 0; it < 2; ++it) {
            int slot = tid + it * 256;          // 0..511
            int row = slot >> 2;                // 0..127
            int kq  = (slot & 3) * 4;           // 0,4,8,12
            float4 av = *(const float4*)(A  + (size_t)(m0 + row) * K + k0 + kq);
            float4 bv = *(const float4*)(Bm + (size_t)(n0 + row) * K + k0 + kq);
            As[kq + 0][row] = av.x; As[kq + 1][row] = av.y;
            As[kq + 2][row] = av.z; As[kq + 3][row] = av.w;
            Bs[kq + 0][row] = bv.x; Bs[kq + 1][row] = bv.y;
            Bs[kq + 2][row] = bv.z; Bs[kq + 3][row] = bv.w;
        }
        __syncthreads();
#pragma unroll
        for (int kk = 0; kk < BK; ++kk) {
            float a[8], b[8];
#pragma unroll
            for (int i = 0; i < 8; ++i) a[i] = As[kk][ty * 8 + i];
#pragma unroll
            for (int j = 0; j < 8; ++j) b[j] = Bs[kk][tx * 8 + j];
#pragma unroll
            for (int i = 0; i < 8; ++i)
#pragma unroll
                for (int j = 0; j < 8; ++j)
                    acc[i][j] = fmaf(a[i], b[j], acc[i][j]);
        }
    }

#pragma unroll
    for (int i = 0; i < 8; ++i) {
        int m = m0 + ty * 8 + i;
#pragma unroll
        for (int j = 0; j < 8; ++j) {
            int n = n0 + tx * 8 + j;
            float val = acc[i][j];
            if (ACT == 1) val = (val > 0.f) ? (val + 1.f) : expf(val);
            if (ACT == 2) val += bias[n];
            C[(size_t)m * N + n] = val;
        }
    }
}

// ------------- kv & k_sum partials: per (b,h) x s-chunk -------------
__global__ __launch_bounds__(256) void kv_partial_k(
    const float* __restrict__ kf, const float* __restrict__ vv,
    float* __restrict__ kvp, float* __restrict__ ksp)
{
    __shared__ float kfs[8][64];
    __shared__ float vs[8][64];
    const int bh = blockIdx.x;        // 0..63
    const int chunk = blockIdx.y;     // 0..SPLIT-1
    const int b = bh >> 4, h = bh & 15;
    const int tid = threadIdx.x;
    const int col = tid & 63, rg = tid >> 6;      // rg 0..3
    const int tx = tid & 15, ty = tid >> 4;
    const int di0 = ty * 4, dj0 = tx * 4;

    float acc[4][4] = {};
    float ks[4] = {0.f, 0.f, 0.f, 0.f};

    const int rows = 4096 / SPLIT;                 // 512
    const size_t base = ((size_t)b * 4096 + (size_t)chunk * rows) * DMODEL + h * DH;

    for (int it = 0; it < rows / 8; ++it) {
        __syncthreads();
#pragma unroll
        for (int p = 0; p < 2; ++p) {
            int r = rg + p * 4;
            size_t g = base + (size_t)(it * 8 + r) * DMODEL + col;
            kfs[r][col] = kf[g];
            vs[r][col]  = vv[g];
        }
        __syncthreads();
#pragma unroll
        for (int r = 0; r < 8; ++r) {
            float a[4], bb[4];
#pragma unroll
            for (int i = 0; i < 4; ++i) a[i] = kfs[r][di0 + i];
#pragma unroll
            for (int j = 0; j < 4; ++j) bb[j] = vs[r][dj0 + j];
#pragma unroll
            for (int i = 0; i < 4; ++i)
#pragma unroll
                for (int j = 0; j < 4; ++j)
                    acc[i][j] = fmaf(a[i], bb[j], acc[i][j]);
            if (tx == 0) {
#pragma unroll
                for (int i = 0; i < 4; ++i) ks[i] += a[i];
            }
        }
    }

    const size_t obase = ((size_t)chunk * 64 + bh) * (DH * DH);
#pragma unroll
    for (int i = 0; i < 4; ++i)
#pragma unroll
        for (int j = 0; j < 4; ++j)
            kvp[obase + (size_t)(di0 + i) * DH + dj0 + j] = acc[i][j];
    if (tx == 0) {
        size_t kb = ((size_t)chunk * 64 + bh) * DH + di0;
#pragma unroll
        for (int i = 0; i < 4; ++i) ksp[kb + i] = ks[i];
    }
}

// ------------- reduce partials -------------
__global__ __launch_bounds__(256) void reduce_kv_k(
    const float* __restrict__ kvp, const float* __restrict__ ksp,
    float* __restrict__ kv, float* __restrict__ ksum)
{
    int idx = blockIdx.x * 256 + threadIdx.x;     // 0..262143
    float s = 0.f;
    for (int c = 0; c < SPLIT; ++c) s += kvp[(size_t)c * (64 * DH * DH) + idx];
    kv[idx] = s;
    if (idx < 64 * DH) {
        float t = 0.f;
        for (int c = 0; c < SPLIT; ++c) t += ksp[(size_t)c * (64 * DH) + idx];
        ksum[idx] = t;
    }
}

// ------------- attn apply: q_kv / denom, in-place over qf -------------
__global__ __launch_bounds__(256) void attn_out_k(
    const float* qf_in, const float* __restrict__ kv,
    const float* __restrict__ ksum, float* attn)
{
    __shared__ float kvs[DH * DH];
    __shared__ float qfs[16][DH];
    __shared__ float ksums[DH];
    __shared__ float denoms[16];
    const int h = blockIdx.y;
    const int t0 = blockIdx.x * 16;
    const int b = t0 >> 12;
    const int bh = b * NHEAD + h;
    const int tid = threadIdx.x;

    for (int i = tid; i < DH * DH; i += 256) kvs[i] = kv[(size_t)bh * (DH * DH) + i];
    for (int i = tid; i < 16 * DH; i += 256) {
        int tok = i >> 6, e = i & 63;
        qfs[tok][e] = qf_in[(size_t)(t0 + tok) * DMODEL + h * DH + e];
    }
    if (tid < DH) ksums[tid] = ksum[(size_t)bh * DH + tid];
    __syncthreads();
    if (tid < 16) {
        float d = 0.f;
#pragma unroll
        for (int i = 0; i < DH; ++i) d += qfs[tid][i] * ksums[i];
        denoms[tid] = d + 1e-6f;
    }
    __syncthreads();
#pragma unroll
    for (int k = 0; k < 4; ++k) {
        int o = tid + k * 256;                    // 0..1023
        int tok = o >> 6, e = o & 63;
        float s = 0.f;
#pragma unroll
        for (int d = 0; d < DH; ++d) s = fmaf(qfs[tok][d], kvs[d * DH + e], s);
        attn[(size_t)(t0 + tok) * DMODEL + h * DH + e] = s / denoms[tok];
    }
}

extern "C" void kernel_launch(void* const* d_in, const int* in_sizes, int n_in,
                              void* d_out, int out_size, void* d_ws, size_t ws_size,
                              hipStream_t stream)
{
    const float* x  = (const float*)d_in[0];
    const float* wq = (const float*)d_in[1];
    const float* wk = (const float*)d_in[2];
    const float* wv = (const float*)d_in[3];
    const float* wo = (const float*)d_in[4];
    const float* bo = (const float*)d_in[5];
    float* out = (float*)d_out;

    float* kf   = (float*)d_ws;
    float* vv   = kf  + (size_t)TOK * DMODEL;
    float* qf   = vv  + (size_t)TOK * DMODEL;
    float* kvp  = qf  + (size_t)TOK * DMODEL;
    float* ksp  = kvp + (size_t)SPLIT * 64 * DH * DH;
    float* kv   = ksp + (size_t)SPLIT * 64 * DH;
    float* ksum = kv  + (size_t)64 * DH * DH;

    const dim3 ggrid(DMODEL / BN, TOK / BM);   // (8, 128)

    // Q/K/V projections (+ feature map on q,k)
    gemm_bt_k<1><<<ggrid, 256, 0, stream>>>(x, wq, nullptr, qf, TOK, DMODEL, DMODEL);
    gemm_bt_k<1><<<ggrid, 256, 0, stream>>>(x, wk, nullptr, kf, TOK, DMODEL, DMODEL);
    gemm_bt_k<0><<<ggrid, 256, 0, stream>>>(x, wv, nullptr, vv, TOK, DMODEL, DMODEL);

    // kv = kf^T @ v, k_sum = sum_s kf   (split over s, then reduce)
    kv_partial_k<<<dim3(64, SPLIT), 256, 0, stream>>>(kf, vv, kvp, ksp);
    reduce_kv_k<<<dim3(64 * DH * DH / 256), 256, 0, stream>>>(kvp, ksp, kv, ksum);

    // attn = (qf @ kv) / (qf . ksum + eps), in-place over qf
    attn_out_k<<<dim3(TOK / 16, NHEAD), 256, 0, stream>>>(qf, kv, ksum, qf);

    // out = attn @ wo^T + bo
    gemm_bt_k<2><<<ggrid, 256, 0, stream>>>(qf, wo, bo, out, TOK, DMODEL, DMODEL);
}

// Round 3
// 765.541 us; speedup vs baseline: 2.2760x; 2.2760x over previous
//
#include <hip/hip_runtime.h>
#include <hip/hip_bf16.h>
#include <cmath>

// b=4, s=4096, d=1024, h=16, dh=64.  TOK = 16384.
// Split-bf16 MFMA for the four big GEMMs (hi*hi + hi*lo + lo*hi),
// fp32 vector path for the per-head linear-attention middle.
// ws budget kept <= ~182 MiB (round-1-proven 201 MiB ceiling).

#define TOK    16384
#define DMODEL 1024
#define NHEAD  16
#define DH     64

using bf16x8 = __attribute__((ext_vector_type(8))) short;
using f32x4  = __attribute__((ext_vector_type(4))) float;

typedef __attribute__((address_space(1))) const unsigned int gld_src_t;
typedef __attribute__((address_space(3))) unsigned int gld_dst_t;

__device__ __forceinline__ unsigned short f2bf(float x) {
    unsigned int u = __float_as_uint(x);
    u += 0x7fffu + ((u >> 16) & 1u);          // round-to-nearest-even
    return (unsigned short)(u >> 16);
}
__device__ __forceinline__ float bf2f(unsigned short b) {
    return __uint_as_float((unsigned int)b << 16);
}

// ---------------- split fp32 -> bf16 hi/lo ----------------
__global__ __launch_bounds__(256) void split_k(
    const float* __restrict__ in, unsigned short* __restrict__ hi,
    unsigned short* __restrict__ lo, int n)
{
    int i = (blockIdx.x * 256 + threadIdx.x) * 4;
    if (i >= n) return;
    float4 v = *(const float4*)(in + i);
    float vs[4] = {v.x, v.y, v.z, v.w};
    unsigned short hh[4], ll[4];
#pragma unroll
    for (int j = 0; j < 4; ++j) {
        unsigned short h = f2bf(vs[j]);
        hh[j] = h;
        ll[j] = f2bf(vs[j] - bf2f(h));
    }
    *(ushort4*)(hi + i) = make_ushort4(hh[0], hh[1], hh[2], hh[3]);
    *(ushort4*)(lo + i) = make_ushort4(ll[0], ll[1], ll[2], ll[3]);
}

// ---------------- split-bf16 MFMA GEMM: C[M,N] = A[M,K] @ B[N,K]^T ----------------
// ACT: 0 none, 1 elu+1, 2 +bias.   128x128 tile, BK=32, 4 waves (2x2), 64x64/wave.
template<int ACT>
__global__ __launch_bounds__(256) void gemm3_k(
    const unsigned short* __restrict__ Ah, const unsigned short* __restrict__ Al,
    const unsigned short* __restrict__ Bh, const unsigned short* __restrict__ Bl,
    const float* __restrict__ bias, float* __restrict__ C,
    int M, int N, int K)
{
    __shared__ unsigned short lds[4][128 * 32];   // Ah, Al, Bh, Bl tiles: 8 KB each
    const int tid  = threadIdx.x;
    const int lane = tid & 63, wid = tid >> 6;
    const int m0 = blockIdx.y * 128, n0 = blockIdx.x * 128;
    const int wr = wid >> 1, wc = wid & 1;

    f32x4 acc[4][4];
#pragma unroll
    for (int i = 0; i < 4; ++i)
#pragma unroll
        for (int j = 0; j < 4; ++j) acc[i][j] = (f32x4){0.f, 0.f, 0.f, 0.f};

    // staging: wave wid stages tile wid (Ah/Al/Bh/Bl), 8 segs of 1 KiB
    const unsigned short* srcb = (wid == 0) ? Ah : (wid == 1) ? Al : (wid == 2) ? Bh : Bl;
    const int rowbase = (wid < 2) ? m0 : n0;
    const int srow = lane >> 2;     // row within 16-row segment
    const int sslot = lane & 3;     // 16B slot within 64B row
    unsigned short* ldsbase = &lds[wid][0];

    const int fr = lane & 15;       // fragment row (A) / col (B)
    const int ko = lane >> 4;       // k-offset group: k = ko*8 + j

    for (int k0 = 0; k0 < K; k0 += 32) {
        __syncthreads();            // previous compute done before overwrite
#pragma unroll
        for (int t = 0; t < 8; ++t) {
            int row  = t * 16 + srow;
            int slot = sslot ^ ((row >> 1) & 3);   // pre-swizzled source (rule #21)
            const unsigned short* g = srcb + (size_t)(rowbase + row) * K + k0 + slot * 8;
            __builtin_amdgcn_global_load_lds((gld_src_t*)g, (gld_dst_t*)(ldsbase + t * 512), 16, 0, 0);
        }
        __syncthreads();            // vmcnt(0) drained before barrier -> tiles ready

        bf16x8 ah[4], al[4];
#pragma unroll
        for (int mi = 0; mi < 4; ++mi) {
            int row = wr * 64 + mi * 16 + fr;
            int off = row * 32 + ((ko ^ ((row >> 1) & 3)) * 8);   // swizzled read
            ah[mi] = *(const bf16x8*)&lds[0][off];
            al[mi] = *(const bf16x8*)&lds[1][off];
        }
#pragma unroll
        for (int nj = 0; nj < 4; ++nj) {
            int row = wc * 64 + nj * 16 + fr;
            int off = row * 32 + ((ko ^ ((row >> 1) & 3)) * 8);
            bf16x8 bh = *(const bf16x8*)&lds[2][off];
            bf16x8 bl = *(const bf16x8*)&lds[3][off];
#pragma unroll
            for (int mi = 0; mi < 4; ++mi) {
                acc[mi][nj] = __builtin_amdgcn_mfma_f32_16x16x32_bf16(ah[mi], bh, acc[mi][nj], 0, 0, 0);
                acc[mi][nj] = __builtin_amdgcn_mfma_f32_16x16x32_bf16(ah[mi], bl, acc[mi][nj], 0, 0, 0);
                acc[mi][nj] = __builtin_amdgcn_mfma_f32_16x16x32_bf16(al[mi], bh, acc[mi][nj], 0, 0, 0);
            }
        }
    }

    // C/D layout: row=(lane>>4)*4+i, col=lane&15  [m89-verified]
    const int fq = lane >> 4;
#pragma unroll
    for (int mi = 0; mi < 4; ++mi) {
#pragma unroll
        for (int i = 0; i < 4; ++i) {
            int m = m0 + wr * 64 + mi * 16 + fq * 4 + i;
            float* crow = C + (size_t)m * N + n0 + wc * 64;
#pragma unroll
            for (int nj = 0; nj < 4; ++nj) {
                int n = nj * 16 + fr;
                float v = acc[mi][nj][i];
                if (ACT == 1) v = (v > 0.f) ? (v + 1.f) : expf(v);
                if (ACT == 2) v += bias[n0 + wc * 64 + n];
                crow[n] = v;
            }
        }
    }
}

// ------------- kv & k_sum partials for one 2-batch chunk -------------
// grid (32 local bh, 4 s-splits).  vchunk holds 8192 tokens (2 batches).
__global__ __launch_bounds__(256) void kv_partial_k(
    const float* __restrict__ kf, const float* __restrict__ vchunk,
    int bh_base, float* __restrict__ kvp, float* __restrict__ ksp)
{
    __shared__ float kfs[8][64];
    __shared__ float vs[8][64];
    const int bh = bh_base + blockIdx.x;      // global bh 0..63
    const int split = blockIdx.y;             // 0..3
    const int b = bh >> 4, h = bh & 15;
    const int blocal = b - (bh_base >> 4);    // 0..1 within chunk
    const int tid = threadIdx.x;
    const int col = tid & 63, rg = tid >> 6;
    const int tx = tid & 15, ty = tid >> 4;
    const int di0 = ty * 4, dj0 = tx * 4;

    float acc[4][4] = {};
    float ks[4] = {0.f, 0.f, 0.f, 0.f};

    const int rows = 1024;                    // 4096 / 4 splits
    const size_t kbase = ((size_t)b * 4096 + (size_t)split * rows) * DMODEL + h * DH;
    const size_t vbase = ((size_t)blocal * 4096 + (size_t)split * rows) * DMODEL + h * DH;

    for (int it = 0; it < rows / 8; ++it) {
        __syncthreads();
#pragma unroll
        for (int p = 0; p < 2; ++p) {
            int r = rg + p * 4;
            size_t o = (size_t)(it * 8 + r) * DMODEL + col;
            kfs[r][col] = kf[kbase + o];
            vs[r][col]  = vchunk[vbase + o];
        }
        __syncthreads();
#pragma unroll
        for (int r = 0; r < 8; ++r) {
            float a[4], bb[4];
#pragma unroll
            for (int i = 0; i < 4; ++i) a[i] = kfs[r][di0 + i];
#pragma unroll
            for (int j = 0; j < 4; ++j) bb[j] = vs[r][dj0 + j];
#pragma unroll
            for (int i = 0; i < 4; ++i)
#pragma unroll
                for (int j = 0; j < 4; ++j)
                    acc[i][j] = fmaf(a[i], bb[j], acc[i][j]);
            if (tx == 0) {
#pragma unroll
                for (int i = 0; i < 4; ++i) ks[i] += a[i];
            }
        }
    }

    const size_t obase = ((size_t)(bh * 4 + split)) * (DH * DH);
#pragma unroll
    for (int i = 0; i < 4; ++i)
#pragma unroll
        for (int j = 0; j < 4; ++j)
            kvp[obase + (size_t)(di0 + i) * DH + dj0 + j] = acc[i][j];
    if (tx == 0) {
        size_t kb = ((size_t)(bh * 4 + split)) * DH + di0;
#pragma unroll
        for (int i = 0; i < 4; ++i) ksp[kb + i] = ks[i];
    }
}

__global__ __launch_bounds__(256) void reduce_kv_k(
    const float* __restrict__ kvp, const float* __restrict__ ksp,
    float* __restrict__ kv, float* __restrict__ ksum)
{
    int idx = blockIdx.x * 256 + threadIdx.x;     // 0..262143
    int bh = idx >> 12, off = idx & 4095;
    float s = 0.f;
    for (int c = 0; c < 4; ++c) s += kvp[((size_t)(bh * 4 + c)) * 4096 + off];
    kv[idx] = s;
    if (idx < 64 * DH) {
        int bh2 = idx >> 6, o2 = idx & 63;
        float t = 0.f;
        for (int c = 0; c < 4; ++c) t += ksp[((size_t)(bh2 * 4 + c)) * DH + o2];
        ksum[idx] = t;
    }
}

// ------------- attn apply + hi/lo re-split for final GEMM -------------
__global__ __launch_bounds__(256) void attn_out_k(
    const float* __restrict__ qf_in, const float* __restrict__ kv,
    const float* __restrict__ ksum, unsigned short* __restrict__ out_hi,
    unsigned short* __restrict__ out_lo)
{
    __shared__ float kvs[DH * DH];
    __shared__ float qfs[16][DH];
    __shared__ float ksums[DH];
    __shared__ float denoms[16];
    const int hh = blockIdx.y;
    const int t0 = blockIdx.x * 16;
    const int b = t0 >> 12;
    const int bh = b * NHEAD + hh;
    const int tid = threadIdx.x;

    for (int i = tid; i < DH * DH; i += 256) kvs[i] = kv[(size_t)bh * (DH * DH) + i];
    for (int i = tid; i < 16 * DH; i += 256) {
        int tok = i >> 6, e = i & 63;
        qfs[tok][e] = qf_in[(size_t)(t0 + tok) * DMODEL + hh * DH + e];
    }
    if (tid < DH) ksums[tid] = ksum[(size_t)bh * DH + tid];
    __syncthreads();
    if (tid < 16) {
        float d = 0.f;
#pragma unroll
        for (int i = 0; i < DH; ++i) d += qfs[tid][i] * ksums[i];
        denoms[tid] = d + 1e-6f;
    }
    __syncthreads();
#pragma unroll
    for (int k = 0; k < 4; ++k) {
        int o = tid + k * 256;
        int tok = o >> 6, e = o & 63;
        float s = 0.f;
#pragma unroll
        for (int d = 0; d < DH; ++d) s = fmaf(qfs[tok][d], kvs[d * DH + e], s);
        s /= denoms[tok];
        size_t idx = (size_t)(t0 + tok) * DMODEL + hh * DH + e;
        unsigned short hb = f2bf(s);
        out_hi[idx] = hb;
        out_lo[idx] = f2bf(s - bf2f(hb));
    }
}

extern "C" void kernel_launch(void* const* d_in, const int* in_sizes, int n_in,
                              void* d_out, int out_size, void* d_ws, size_t ws_size,
                              hipStream_t stream)
{
    const float* x  = (const float*)d_in[0];
    const float* wq = (const float*)d_in[1];
    const float* wk = (const float*)d_in[2];
    const float* wv = (const float*)d_in[3];
    const float* wo = (const float*)d_in[4];
    const float* bo = (const float*)d_in[5];
    float* out = (float*)d_out;

    const size_t XE = (size_t)TOK * DMODEL;       // 16 M elements
    const size_t WE = (size_t)DMODEL * DMODEL;    // 1 M elements
    const size_t CE = (size_t)8192 * DMODEL;      // 8 M (half-token chunk)

    // ws layout (<= ~182 MiB)
    unsigned short* xh  = (unsigned short*)d_ws;           // 32 MiB
    unsigned short* xl  = xh + XE;                          // 32 MiB
    unsigned short* wqh = xl + XE;                          // 8 x 2 MiB
    unsigned short* wql = wqh + WE;
    unsigned short* wkh = wql + WE;
    unsigned short* wkl = wkh + WE;
    unsigned short* wvh = wkl + WE;
    unsigned short* wvl = wvh + WE;
    unsigned short* woh = wvl + WE;
    unsigned short* wol = woh + WE;
    float* kf   = (float*)(wol + WE);                       // 64 MiB (reused as qf)
    float* vc   = kf + XE;                                  // 32 MiB (v chunk)
    float* kvp  = vc + CE;                                  // 4 MiB (64 bh x 4 splits x 64x64)
    float* ksp  = kvp + (size_t)64 * 4 * DH * DH;           // 64 KiB
    float* kvb  = ksp + (size_t)64 * 4 * DH;                // 1 MiB
    float* ksmb = kvb + (size_t)64 * DH * DH;               // 16 KiB
    float* qf   = kf;                                       // alias: kf dead after kv

    // decompose inputs to bf16 hi/lo
    split_k<<<(int)(XE / 1024), 256, 0, stream>>>(x, xh, xl, (int)XE);
    split_k<<<(int)(WE / 1024), 256, 0, stream>>>(wq, wqh, wql, (int)WE);
    split_k<<<(int)(WE / 1024), 256, 0, stream>>>(wk, wkh, wkl, (int)WE);
    split_k<<<(int)(WE / 1024), 256, 0, stream>>>(wv, wvh, wvl, (int)WE);
    split_k<<<(int)(WE / 1024), 256, 0, stream>>>(wo, woh, wol, (int)WE);

    const dim3 ggrid(DMODEL / 128, TOK / 128);    // (8, 128)
    const dim3 cgrid(DMODEL / 128, 8192 / 128);   // (8, 64)

    // k projection (full), then v projection + kv partials per 2-batch chunk
    gemm3_k<1><<<ggrid, 256, 0, stream>>>(xh, xl, wkh, wkl, nullptr, kf, TOK, DMODEL, DMODEL);

    gemm3_k<0><<<cgrid, 256, 0, stream>>>(xh, xl, wvh, wvl, nullptr, vc, 8192, DMODEL, DMODEL);
    kv_partial_k<<<dim3(32, 4), 256, 0, stream>>>(kf, vc, 0, kvp, ksp);

    gemm3_k<0><<<cgrid, 256, 0, stream>>>(xh + CE, xl + CE, wvh, wvl, nullptr, vc, 8192, DMODEL, DMODEL);
    kv_partial_k<<<dim3(32, 4), 256, 0, stream>>>(kf, vc, 32, kvp, ksp);

    reduce_kv_k<<<dim3(64 * DH * DH / 256), 256, 0, stream>>>(kvp, ksp, kvb, ksmb);

    // q projection into kf's region (kf dead), then attn apply -> xh/xl
    gemm3_k<1><<<ggrid, 256, 0, stream>>>(xh, xl, wqh, wql, nullptr, qf, TOK, DMODEL, DMODEL);
    attn_out_k<<<dim3(TOK / 16, NHEAD), 256, 0, stream>>>(qf, kvb, ksmb, xh, xl);

    gemm3_k<2><<<ggrid, 256, 0, stream>>>(xh, xl, woh, wol, bo, out, TOK, DMODEL, DMODEL);
}

// Round 4
// 695.584 us; speedup vs baseline: 2.5049x; 1.1006x over previous
//
#include <hip/hip_runtime.h>
#include <hip/hip_bf16.h>
#include <cmath>

// b=4, s=4096, d=1024, h=16, dh=64.  TOK = 16384.
// Split-bf16 (hi/lo) 32x32x16 MFMA for the four big GEMMs,
// fp32 vector path for the per-head linear-attention middle.
// ws <= ~185 MiB.

#define TOK    16384
#define DMODEL 1024
#define NHEAD  16
#define DH     64
#define KSPLIT 8

using bf16x8 = __attribute__((ext_vector_type(8))) short;
using f32x16 = __attribute__((ext_vector_type(16))) float;

typedef __attribute__((address_space(1))) const unsigned int gld_src_t;
typedef __attribute__((address_space(3))) unsigned int gld_dst_t;

__device__ __forceinline__ unsigned short f2bf(float x) {
    unsigned int u = __float_as_uint(x);
    u += 0x7fffu + ((u >> 16) & 1u);          // RNE
    return (unsigned short)(u >> 16);
}
__device__ __forceinline__ float bf2f(unsigned short b) {
    return __uint_as_float((unsigned int)b << 16);
}

// ---------------- split fp32 -> bf16 hi/lo ----------------
__global__ __launch_bounds__(256) void split_k(
    const float* __restrict__ in, unsigned short* __restrict__ hi,
    unsigned short* __restrict__ lo, int n)
{
    int i = (blockIdx.x * 256 + threadIdx.x) * 4;
    if (i >= n) return;
    float4 v = *(const float4*)(in + i);
    float vs[4] = {v.x, v.y, v.z, v.w};
    unsigned short hh[4], ll[4];
#pragma unroll
    for (int j = 0; j < 4; ++j) {
        unsigned short h = f2bf(vs[j]);
        hh[j] = h;
        ll[j] = f2bf(vs[j] - bf2f(h));
    }
    *(ushort4*)(hi + i) = make_ushort4(hh[0], hh[1], hh[2], hh[3]);
    *(ushort4*)(lo + i) = make_ushort4(ll[0], ll[1], ll[2], ll[3]);
}

// all four weight matrices in one dispatch (4096 blocks)
__global__ __launch_bounds__(256) void splitw_k(
    const float* __restrict__ w0, const float* __restrict__ w1,
    const float* __restrict__ w2, const float* __restrict__ w3,
    unsigned short* __restrict__ hs, unsigned short* __restrict__ ls)
{
    int w = blockIdx.x >> 10;
    const float* src = (w == 0) ? w0 : (w == 1) ? w1 : (w == 2) ? w2 : w3;
    int i = ((blockIdx.x & 1023) * 256 + threadIdx.x) * 4;
    size_t base = (size_t)w * (DMODEL * DMODEL);
    float4 v = *(const float4*)(src + i);
    float vs[4] = {v.x, v.y, v.z, v.w};
    unsigned short hh[4], ll[4];
#pragma unroll
    for (int j = 0; j < 4; ++j) {
        unsigned short h = f2bf(vs[j]);
        hh[j] = h;
        ll[j] = f2bf(vs[j] - bf2f(h));
    }
    *(ushort4*)(hs + base + i) = make_ushort4(hh[0], hh[1], hh[2], hh[3]);
    *(ushort4*)(ls + base + i) = make_ushort4(ll[0], ll[1], ll[2], ll[3]);
}

// ------------- split-bf16 32x32x16 MFMA GEMM: C[M,N] = A[M,K] @ B[N,K]^T -------------
// ACT: 0 none, 1 elu+1, 2 +bias.  128x128 tile, BK=32, 4 waves (2x2), 64x64/wave.
// 1D grid with bijective XCD swizzle (ncols is always DMODEL/128 = 8).
template<int ACT>
__global__ __launch_bounds__(256) void gemm32_k(
    const unsigned short* __restrict__ Ah, const unsigned short* __restrict__ Al,
    const unsigned short* __restrict__ Bh, const unsigned short* __restrict__ Bl,
    const float* __restrict__ bias, float* __restrict__ C,
    int M, int N, int K)
{
    __shared__ unsigned short lds[4][128 * 32];   // Ah, Al, Bh, Bl tiles: 8 KB each
    const int tid  = threadIdx.x;
    const int lane = tid & 63, wid = tid >> 6;

    // XCD swizzle: 8 XCDs get contiguous row-panel chunks (nwg % 8 == 0)
    const int nwg = gridDim.x, cpx = nwg >> 3, lin = blockIdx.x;
    const int swz = (lin & 7) * cpx + (lin >> 3);
    const int m0 = (swz >> 3) * 128, n0 = (swz & 7) * 128;

    const int wr = wid >> 1, wc = wid & 1;

    f32x16 acc[2][2];
#pragma unroll
    for (int i = 0; i < 2; ++i)
#pragma unroll
        for (int j = 0; j < 2; ++j)
#pragma unroll
            for (int r = 0; r < 16; ++r) acc[i][j][r] = 0.f;

    // staging: wave wid stages tile wid (Ah/Al/Bh/Bl), 8 segs of 1 KiB
    const unsigned short* srcb = (wid == 0) ? Ah : (wid == 1) ? Al : (wid == 2) ? Bh : Bl;
    const int rowbase = (wid < 2) ? m0 : n0;
    const int srow = lane >> 2;     // row within 16-row segment
    const int sslot = lane & 3;     // 16B slot within 64B row
    unsigned short* ldsbase = &lds[wid][0];

    const int r32 = lane & 31;      // fragment row (A) / col (B) within 32-block
    const int kg  = lane >> 5;      // k-group: k = ks*16 + kg*8 + j

    for (int k0 = 0; k0 < K; k0 += 32) {
        __syncthreads();            // previous compute done before overwrite
#pragma unroll
        for (int t = 0; t < 8; ++t) {
            int row  = t * 16 + srow;
            int slot = sslot ^ ((row >> 1) & 3);   // pre-swizzled source (rule #21)
            const unsigned short* g = srcb + (size_t)(rowbase + row) * K + k0 + slot * 8;
            __builtin_amdgcn_global_load_lds((gld_src_t*)g, (gld_dst_t*)(ldsbase + t * 512), 16, 0, 0);
        }
        __syncthreads();            // tiles ready

#pragma unroll
        for (int ks = 0; ks < 2; ++ks) {
            bf16x8 ah[2], al[2], bh[2], bl[2];
#pragma unroll
            for (int mi = 0; mi < 2; ++mi) {
                int row = wr * 64 + mi * 32 + r32;
                int off = row * 32 + ((ks * 2 + kg) ^ ((row >> 1) & 3)) * 8;
                ah[mi] = *(const bf16x8*)&lds[0][off];
                al[mi] = *(const bf16x8*)&lds[1][off];
            }
#pragma unroll
            for (int nj = 0; nj < 2; ++nj) {
                int row = wc * 64 + nj * 32 + r32;
                int off = row * 32 + ((ks * 2 + kg) ^ ((row >> 1) & 3)) * 8;
                bh[nj] = *(const bf16x8*)&lds[2][off];
                bl[nj] = *(const bf16x8*)&lds[3][off];
            }
#pragma unroll
            for (int mi = 0; mi < 2; ++mi)
#pragma unroll
                for (int nj = 0; nj < 2; ++nj) {
                    acc[mi][nj] = __builtin_amdgcn_mfma_f32_32x32x16_bf16(ah[mi], bh[nj], acc[mi][nj], 0, 0, 0);
                    acc[mi][nj] = __builtin_amdgcn_mfma_f32_32x32x16_bf16(ah[mi], bl[nj], acc[mi][nj], 0, 0, 0);
                    acc[mi][nj] = __builtin_amdgcn_mfma_f32_32x32x16_bf16(al[mi], bh[nj], acc[mi][nj], 0, 0, 0);
                }
        }
    }

    // C/D layout (32x32): col=lane&31, row=(reg&3)+8*(reg>>2)+4*(lane>>5)  [m74/m101]
#pragma unroll
    for (int mi = 0; mi < 2; ++mi)
#pragma unroll
        for (int nj = 0; nj < 2; ++nj) {
            int n = n0 + wc * 64 + nj * 32 + r32;
#pragma unroll
            for (int reg = 0; reg < 16; ++reg) {
                int rrow = (reg & 3) + 8 * (reg >> 2) + 4 * kg;
                int m = m0 + wr * 64 + mi * 32 + rrow;
                float v = acc[mi][nj][reg];
                if (ACT == 1) v = (v > 0.f) ? (v + 1.f) : expf(v);
                if (ACT == 2) v += bias[n];
                C[(size_t)m * N + n] = v;
            }
        }
}

// ------------- kv & k_sum partials for one 2-batch chunk -------------
// grid (32 local bh, KSPLIT s-splits).  vchunk holds 8192 tokens (2 batches).
__global__ __launch_bounds__(256) void kv_partial_k(
    const float* __restrict__ kf, const float* __restrict__ vchunk,
    int bh_base, float* __restrict__ kvp, float* __restrict__ ksp)
{
    __shared__ float kfs[8][64];
    __shared__ float vs[8][64];
    const int bh = bh_base + blockIdx.x;      // global bh 0..63
    const int split = blockIdx.y;             // 0..KSPLIT-1
    const int b = bh >> 4, h = bh & 15;
    const int blocal = b - (bh_base >> 4);    // 0..1 within chunk
    const int tid = threadIdx.x;
    const int col = tid & 63, rg = tid >> 6;
    const int tx = tid & 15, ty = tid >> 4;
    const int di0 = ty * 4, dj0 = tx * 4;

    float acc[4][4] = {};
    float ks[4] = {0.f, 0.f, 0.f, 0.f};

    const int rows = 4096 / KSPLIT;           // 512
    const size_t kbase = ((size_t)b * 4096 + (size_t)split * rows) * DMODEL + h * DH;
    const size_t vbase = ((size_t)blocal * 4096 + (size_t)split * rows) * DMODEL + h * DH;

    for (int it = 0; it < rows / 8; ++it) {
        __syncthreads();
#pragma unroll
        for (int p = 0; p < 2; ++p) {
            int r = rg + p * 4;
            size_t o = (size_t)(it * 8 + r) * DMODEL + col;
            kfs[r][col] = kf[kbase + o];
            vs[r][col]  = vchunk[vbase + o];
        }
        __syncthreads();
#pragma unroll
        for (int r = 0; r < 8; ++r) {
            float a[4], bb[4];
#pragma unroll
            for (int i = 0; i < 4; ++i) a[i] = kfs[r][di0 + i];
#pragma unroll
            for (int j = 0; j < 4; ++j) bb[j] = vs[r][dj0 + j];
#pragma unroll
            for (int i = 0; i < 4; ++i)
#pragma unroll
                for (int j = 0; j < 4; ++j)
                    acc[i][j] = fmaf(a[i], bb[j], acc[i][j]);
            if (tx == 0) {
#pragma unroll
                for (int i = 0; i < 4; ++i) ks[i] += a[i];
            }
        }
    }

    const size_t obase = ((size_t)(bh * KSPLIT + split)) * (DH * DH);
#pragma unroll
    for (int i = 0; i < 4; ++i)
#pragma unroll
        for (int j = 0; j < 4; ++j)
            kvp[obase + (size_t)(di0 + i) * DH + dj0 + j] = acc[i][j];
    if (tx == 0) {
        size_t kb = ((size_t)(bh * KSPLIT + split)) * DH + di0;
#pragma unroll
        for (int i = 0; i < 4; ++i) ksp[kb + i] = ks[i];
    }
}

__global__ __launch_bounds__(256) void reduce_kv_k(
    const float* __restrict__ kvp, const float* __restrict__ ksp,
    float* __restrict__ kv, float* __restrict__ ksum)
{
    int idx = blockIdx.x * 256 + threadIdx.x;     // 0..262143
    int bh = idx >> 12, off = idx & 4095;
    float s = 0.f;
    for (int c = 0; c < KSPLIT; ++c) s += kvp[((size_t)(bh * KSPLIT + c)) * 4096 + off];
    kv[idx] = s;
    if (idx < 64 * DH) {
        int bh2 = idx >> 6, o2 = idx & 63;
        float t = 0.f;
        for (int c = 0; c < KSPLIT; ++c) t += ksp[((size_t)(bh2 * KSPLIT + c)) * DH + o2];
        ksum[idx] = t;
    }
}

// ------------- attn apply + hi/lo re-split for final GEMM -------------
__global__ __launch_bounds__(256) void attn_out_k(
    const float* __restrict__ qf_in, const float* __restrict__ kv,
    const float* __restrict__ ksum, unsigned short* __restrict__ out_hi,
    unsigned short* __restrict__ out_lo)
{
    __shared__ float kvs[DH * DH];
    __shared__ float qfs[16][DH];
    __shared__ float ksums[DH];
    __shared__ float denoms[16];
    const int hh = blockIdx.y;
    const int t0 = blockIdx.x * 16;
    const int b = t0 >> 12;
    const int bh = b * NHEAD + hh;
    const int tid = threadIdx.x;

    for (int i = tid; i < DH * DH; i += 256) kvs[i] = kv[(size_t)bh * (DH * DH) + i];
    for (int i = tid; i < 16 * DH; i += 256) {
        int tok = i >> 6, e = i & 63;
        qfs[tok][e] = qf_in[(size_t)(t0 + tok) * DMODEL + hh * DH + e];
    }
    if (tid < DH) ksums[tid] = ksum[(size_t)bh * DH + tid];
    __syncthreads();
    if (tid < 16) {
        float d = 0.f;
#pragma unroll
        for (int i = 0; i < DH; ++i) d += qfs[tid][i] * ksums[i];
        denoms[tid] = d + 1e-6f;
    }
    __syncthreads();
#pragma unroll
    for (int k = 0; k < 4; ++k) {
        int o = tid + k * 256;
        int tok = o >> 6, e = o & 63;
        float s = 0.f;
#pragma unroll
        for (int d = 0; d < DH; ++d) s = fmaf(qfs[tok][d], kvs[d * DH + e], s);
        s /= denoms[tok];
        size_t idx = (size_t)(t0 + tok) * DMODEL + hh * DH + e;
        unsigned short hb = f2bf(s);
        out_hi[idx] = hb;
        out_lo[idx] = f2bf(s - bf2f(hb));
    }
}

extern "C" void kernel_launch(void* const* d_in, const int* in_sizes, int n_in,
                              void* d_out, int out_size, void* d_ws, size_t ws_size,
                              hipStream_t stream)
{
    const float* x  = (const float*)d_in[0];
    const float* wq = (const float*)d_in[1];
    const float* wk = (const float*)d_in[2];
    const float* wv = (const float*)d_in[3];
    const float* wo = (const float*)d_in[4];
    const float* bo = (const float*)d_in[5];
    float* out = (float*)d_out;

    const size_t XE = (size_t)TOK * DMODEL;       // 16 M elements
    const size_t WE = (size_t)DMODEL * DMODEL;    // 1 M elements
    const size_t CE = (size_t)8192 * DMODEL;      // 8 M (half-token chunk)

    // ws layout (~185 MiB)
    unsigned short* xh = (unsigned short*)d_ws;            // 32 MiB
    unsigned short* xl = xh + XE;                           // 32 MiB
    unsigned short* wh = xl + XE;                           // 8 MiB (q,k,v,o)
    unsigned short* wl = wh + 4 * WE;                       // 8 MiB
    float* kf   = (float*)(wl + 4 * WE);                    // 64 MiB (reused as qf)
    float* vc   = kf + XE;                                  // 32 MiB (v chunk)
    float* kvp  = vc + CE;                                  // 8 MiB
    float* ksp  = kvp + (size_t)64 * KSPLIT * DH * DH;      // 128 KiB
    float* kvb  = ksp + (size_t)64 * KSPLIT * DH;           // 1 MiB
    float* ksmb = kvb + (size_t)64 * DH * DH;               // 16 KiB
    float* qf   = kf;                                       // alias: kf dead after kv

    // decompose inputs to bf16 hi/lo
    split_k<<<(int)(XE / 1024), 256, 0, stream>>>(x, xh, xl, (int)XE);
    splitw_k<<<4096, 256, 0, stream>>>(wq, wk, wv, wo, wh, wl);

    const int gfull = (TOK / 128) * 8;       // 1024 blocks
    const int ghalf = (8192 / 128) * 8;      // 512 blocks

    // k projection (full), then v projection + kv partials per 2-batch chunk
    gemm32_k<1><<<gfull, 256, 0, stream>>>(xh, xl, wh + WE, wl + WE, nullptr, kf, TOK, DMODEL, DMODEL);

    gemm32_k<0><<<ghalf, 256, 0, stream>>>(xh, xl, wh + 2 * WE, wl + 2 * WE, nullptr, vc, 8192, DMODEL, DMODEL);
    kv_partial_k<<<dim3(32, KSPLIT), 256, 0, stream>>>(kf, vc, 0, kvp, ksp);

    gemm32_k<0><<<ghalf, 256, 0, stream>>>(xh + CE, xl + CE, wh + 2 * WE, wl + 2 * WE, nullptr, vc, 8192, DMODEL, DMODEL);
    kv_partial_k<<<dim3(32, KSPLIT), 256, 0, stream>>>(kf, vc, 32, kvp, ksp);

    reduce_kv_k<<<dim3(64 * DH * DH / 256), 256, 0, stream>>>(kvp, ksp, kvb, ksmb);

    // q projection into kf's region (kf dead), then attn apply -> xh/xl
    gemm32_k<1><<<gfull, 256, 0, stream>>>(xh, xl, wh, wl, nullptr, qf, TOK, DMODEL, DMODEL);
    attn_out_k<<<dim3(TOK / 16, NHEAD), 256, 0, stream>>>(qf, kvb, ksmb, xh, xl);

    gemm32_k<2><<<gfull, 256, 0, stream>>>(xh, xl, wh + 3 * WE, wl + 3 * WE, bo, out, TOK, DMODEL, DMODEL);
}

// Round 5
// 584.960 us; speedup vs baseline: 2.9786x; 1.1891x over previous
//
#include <hip/hip_runtime.h>
#include <hip/hip_bf16.h>
#include <cmath>

// b=4, s=4096, d=1024, h=16, dh=64.  TOK = 16384.
// Split-bf16 (hi/lo) 16x16x32 MFMA, 256^2 tile, double-buffered prefetch
// (2-phase) GEMM.  fp32 vector path for the per-head linear-attn middle.
// ws ~185 MiB (proven budget).

#define TOK    16384
#define DMODEL 1024
#define NHEAD  16
#define DH     64
#define KSPLIT 8

using bf16x8 = __attribute__((ext_vector_type(8))) short;
using f32x4  = __attribute__((ext_vector_type(4))) float;

typedef __attribute__((address_space(1))) const unsigned int gld_src_t;
typedef __attribute__((address_space(3))) unsigned int gld_dst_t;

__device__ __forceinline__ unsigned short f2bf(float x) {
    unsigned int u = __float_as_uint(x);
    u += 0x7fffu + ((u >> 16) & 1u);          // RNE
    return (unsigned short)(u >> 16);
}
__device__ __forceinline__ float bf2f(unsigned short b) {
    return __uint_as_float((unsigned int)b << 16);
}

// ---------------- split fp32 -> bf16 hi/lo ----------------
__global__ __launch_bounds__(256) void split_k(
    const float* __restrict__ in, unsigned short* __restrict__ hi,
    unsigned short* __restrict__ lo, int n)
{
    int i = (blockIdx.x * 256 + threadIdx.x) * 4;
    if (i >= n) return;
    float4 v = *(const float4*)(in + i);
    float vs[4] = {v.x, v.y, v.z, v.w};
    unsigned short hh[4], ll[4];
#pragma unroll
    for (int j = 0; j < 4; ++j) {
        unsigned short h = f2bf(vs[j]);
        hh[j] = h;
        ll[j] = f2bf(vs[j] - bf2f(h));
    }
    *(ushort4*)(hi + i) = make_ushort4(hh[0], hh[1], hh[2], hh[3]);
    *(ushort4*)(lo + i) = make_ushort4(ll[0], ll[1], ll[2], ll[3]);
}

// all four weight matrices in one dispatch (4096 blocks)
__global__ __launch_bounds__(256) void splitw_k(
    const float* __restrict__ w0, const float* __restrict__ w1,
    const float* __restrict__ w2, const float* __restrict__ w3,
    unsigned short* __restrict__ hs, unsigned short* __restrict__ ls)
{
    int w = blockIdx.x >> 10;
    const float* src = (w == 0) ? w0 : (w == 1) ? w1 : (w == 2) ? w2 : w3;
    int i = ((blockIdx.x & 1023) * 256 + threadIdx.x) * 4;
    size_t base = (size_t)w * (DMODEL * DMODEL);
    float4 v = *(const float4*)(src + i);
    float vs[4] = {v.x, v.y, v.z, v.w};
    unsigned short hh[4], ll[4];
#pragma unroll
    for (int j = 0; j < 4; ++j) {
        unsigned short h = f2bf(vs[j]);
        hh[j] = h;
        ll[j] = f2bf(vs[j] - bf2f(h));
    }
    *(ushort4*)(hs + base + i) = make_ushort4(hh[0], hh[1], hh[2], hh[3]);
    *(ushort4*)(ls + base + i) = make_ushort4(ll[0], ll[1], ll[2], ll[3]);
}

// ------- split-bf16 256x256 double-buffered GEMM: C[M,N] = A[M,K] @ B[N,K]^T -------
// ACT: 0 none, 1 elu+1, 2 +bias.  BK=32, 8 waves (2Mx4N), per-wave 128x64.
// N is always 1024 (4 col-blocks).  Grid = (M/256)*4, XCD-swizzled.
template<int ACT>
__global__ __launch_bounds__(512, 2) void gemm256_k(
    const unsigned short* __restrict__ Ah, const unsigned short* __restrict__ Al,
    const unsigned short* __restrict__ Bh, const unsigned short* __restrict__ Bl,
    const float* __restrict__ bias, float* __restrict__ C,
    int M, int N, int K)
{
    __shared__ unsigned short lds[2][4][256 * 32];   // [dbuf][Ah,Al,Bh,Bl][256r x 32k]
    const int tid  = threadIdx.x;
    const int lane = tid & 63, wid = tid >> 6;

    // XCD swizzle: 8 XCDs get contiguous m-panel chunks (nwg % 8 == 0)
    const int nwg = gridDim.x, cpx = nwg >> 3;
    const int g = ((int)blockIdx.x & 7) * cpx + ((int)blockIdx.x >> 3);
    const int m0 = (g >> 2) * 256, n0 = (g & 3) * 256;

    const int wr = wid >> 2, wc = wid & 3;       // wave tile: rows wr*128, cols wc*64
    const int fr = lane & 15, ko = lane >> 4;

    f32x4 acc[8][4];
#pragma unroll
    for (int i = 0; i < 8; ++i)
#pragma unroll
        for (int j = 0; j < 4; ++j) acc[i][j] = (f32x4){0.f, 0.f, 0.f, 0.f};

    // ---- staging setup: wave wid stages matrix (wid>>1), 128-row half (wid&1) ----
    const unsigned short* srcb = (wid < 2) ? Ah : (wid < 4) ? Al : (wid < 6) ? Bh : Bl;
    const int rowbase = ((wid < 4) ? m0 : n0) + (wid & 1) * 128;
    const int rloc = (wid & 1) * 128 + (lane >> 2);            // tile row at seg t=0
    const int sslot = (lane & 3) ^ ((rloc >> 1) & 3);          // t-invariant swizzle
    const unsigned short* gsrc0 = srcb + (size_t)(rowbase + (lane >> 2)) * K + sslot * 8;
    const int mat  = wid >> 1;
    const int ldso = ((wid & 1) * 128) * 32;                   // elem offset of half

    // ---- fragment read offsets (16 rows x 4 swizzled slots: proven conflict-free) ----
    const int koff = (ko ^ ((fr >> 1) & 3)) * 8;

    const int nt = K / 32;

    // prologue: stage K-tile 0 into buf 0
#pragma unroll
    for (int t = 0; t < 8; ++t) {
        __builtin_amdgcn_global_load_lds((gld_src_t*)(gsrc0 + (size_t)t * 16 * K),
            (gld_dst_t*)&lds[0][mat][ldso + t * 512], 16, 0, 0);
    }
    __syncthreads();   // drains vmcnt(0): tile 0 ready

    for (int t = 0; t < nt; ++t) {
        const int cur = t & 1;
        // prefetch next K-tile into the other buffer (overlaps with compute)
        if (t + 1 < nt) {
            const unsigned short* gk = gsrc0 + (size_t)(t + 1) * 32;
#pragma unroll
            for (int u = 0; u < 8; ++u) {
                __builtin_amdgcn_global_load_lds((gld_src_t*)(gk + (size_t)u * 16 * K),
                    (gld_dst_t*)&lds[cur ^ 1][mat][ldso + u * 512], 16, 0, 0);
            }
        }
        // compute current tile
        bf16x8 ah[8], al[8];
#pragma unroll
        for (int mi = 0; mi < 8; ++mi) {
            int off = (wr * 128 + mi * 16 + fr) * 32 + koff;
            ah[mi] = *(const bf16x8*)&lds[cur][0][off];
            al[mi] = *(const bf16x8*)&lds[cur][1][off];
        }
#pragma unroll
        for (int nj = 0; nj < 4; ++nj) {
            int off = (wc * 64 + nj * 16 + fr) * 32 + koff;
            bf16x8 bh = *(const bf16x8*)&lds[cur][2][off];
            bf16x8 bl = *(const bf16x8*)&lds[cur][3][off];
#pragma unroll
            for (int mi = 0; mi < 8; ++mi) {
                acc[mi][nj] = __builtin_amdgcn_mfma_f32_16x16x32_bf16(ah[mi], bh, acc[mi][nj], 0, 0, 0);
                acc[mi][nj] = __builtin_amdgcn_mfma_f32_16x16x32_bf16(ah[mi], bl, acc[mi][nj], 0, 0, 0);
                acc[mi][nj] = __builtin_amdgcn_mfma_f32_16x16x32_bf16(al[mi], bh, acc[mi][nj], 0, 0, 0);
            }
        }
        // one barrier per K-tile: __syncthreads() emits vmcnt(0) lgkmcnt(0) drain,
        // so next iteration's reads see a complete buffer and its stores are safe.
        __syncthreads();
    }

    // epilogue: C/D layout row=(lane>>4)*4+i, col=lane&15  [m89-verified]
    const int fq = ko;
#pragma unroll
    for (int mi = 0; mi < 8; ++mi) {
#pragma unroll
        for (int i = 0; i < 4; ++i) {
            int m = m0 + wr * 128 + mi * 16 + fq * 4 + i;
            float* crow = C + (size_t)m * N + n0 + wc * 64;
#pragma unroll
            for (int nj = 0; nj < 4; ++nj) {
                int n = nj * 16 + fr;
                float v = acc[mi][nj][i];
                if (ACT == 1) v = (v > 0.f) ? (v + 1.f) : expf(v);
                if (ACT == 2) v += bias[n0 + wc * 64 + n];
                crow[n] = v;
            }
        }
    }
}

// ------------- kv & k_sum partials for one 2-batch chunk -------------
__global__ __launch_bounds__(256) void kv_partial_k(
    const float* __restrict__ kf, const float* __restrict__ vchunk,
    int bh_base, float* __restrict__ kvp, float* __restrict__ ksp)
{
    __shared__ float kfs[8][64];
    __shared__ float vs[8][64];
    const int bh = bh_base + blockIdx.x;      // global bh 0..63
    const int split = blockIdx.y;             // 0..KSPLIT-1
    const int b = bh >> 4, h = bh & 15;
    const int blocal = b - (bh_base >> 4);    // 0..1 within chunk
    const int tid = threadIdx.x;
    const int col = tid & 63, rg = tid >> 6;
    const int tx = tid & 15, ty = tid >> 4;
    const int di0 = ty * 4, dj0 = tx * 4;

    float acc[4][4] = {};
    float ks[4] = {0.f, 0.f, 0.f, 0.f};

    const int rows = 4096 / KSPLIT;           // 512
    const size_t kbase = ((size_t)b * 4096 + (size_t)split * rows) * DMODEL + h * DH;
    const size_t vbase = ((size_t)blocal * 4096 + (size_t)split * rows) * DMODEL + h * DH;

    for (int it = 0; it < rows / 8; ++it) {
        __syncthreads();
#pragma unroll
        for (int p = 0; p < 2; ++p) {
            int r = rg + p * 4;
            size_t o = (size_t)(it * 8 + r) * DMODEL + col;
            kfs[r][col] = kf[kbase + o];
            vs[r][col]  = vchunk[vbase + o];
        }
        __syncthreads();
#pragma unroll
        for (int r = 0; r < 8; ++r) {
            float a[4], bb[4];
#pragma unroll
            for (int i = 0; i < 4; ++i) a[i] = kfs[r][di0 + i];
#pragma unroll
            for (int j = 0; j < 4; ++j) bb[j] = vs[r][dj0 + j];
#pragma unroll
            for (int i = 0; i < 4; ++i)
#pragma unroll
                for (int j = 0; j < 4; ++j)
                    acc[i][j] = fmaf(a[i], bb[j], acc[i][j]);
            if (tx == 0) {
#pragma unroll
                for (int i = 0; i < 4; ++i) ks[i] += a[i];
            }
        }
    }

    const size_t obase = ((size_t)(bh * KSPLIT + split)) * (DH * DH);
#pragma unroll
    for (int i = 0; i < 4; ++i)
#pragma unroll
        for (int j = 0; j < 4; ++j)
            kvp[obase + (size_t)(di0 + i) * DH + dj0 + j] = acc[i][j];
    if (tx == 0) {
        size_t kb = ((size_t)(bh * KSPLIT + split)) * DH + di0;
#pragma unroll
        for (int i = 0; i < 4; ++i) ksp[kb + i] = ks[i];
    }
}

__global__ __launch_bounds__(256) void reduce_kv_k(
    const float* __restrict__ kvp, const float* __restrict__ ksp,
    float* __restrict__ kv, float* __restrict__ ksum)
{
    int idx = blockIdx.x * 256 + threadIdx.x;     // 0..262143
    int bh = idx >> 12, off = idx & 4095;
    float s = 0.f;
    for (int c = 0; c < KSPLIT; ++c) s += kvp[((size_t)(bh * KSPLIT + c)) * 4096 + off];
    kv[idx] = s;
    if (idx < 64 * DH) {
        int bh2 = idx >> 6, o2 = idx & 63;
        float t = 0.f;
        for (int c = 0; c < KSPLIT; ++c) t += ksp[((size_t)(bh2 * KSPLIT + c)) * DH + o2];
        ksum[idx] = t;
    }
}

// ------------- attn apply + hi/lo re-split for final GEMM -------------
__global__ __launch_bounds__(256) void attn_out_k(
    const float* __restrict__ qf_in, const float* __restrict__ kv,
    const float* __restrict__ ksum, unsigned short* __restrict__ out_hi,
    unsigned short* __restrict__ out_lo)
{
    __shared__ float kvs[DH * DH];
    __shared__ float qfs[16][DH];
    __shared__ float ksums[DH];
    __shared__ float denoms[16];
    const int hh = blockIdx.y;
    const int t0 = blockIdx.x * 16;
    const int b = t0 >> 12;
    const int bh = b * NHEAD + hh;
    const int tid = threadIdx.x;

    for (int i = tid; i < DH * DH; i += 256) kvs[i] = kv[(size_t)bh * (DH * DH) + i];
    for (int i = tid; i < 16 * DH; i += 256) {
        int tok = i >> 6, e = i & 63;
        qfs[tok][e] = qf_in[(size_t)(t0 + tok) * DMODEL + hh * DH + e];
    }
    if (tid < DH) ksums[tid] = ksum[(size_t)bh * DH + tid];
    __syncthreads();
    if (tid < 16) {
        float d = 0.f;
#pragma unroll
        for (int i = 0; i < DH; ++i) d += qfs[tid][i] * ksums[i];
        denoms[tid] = d + 1e-6f;
    }
    __syncthreads();
#pragma unroll
    for (int k = 0; k < 4; ++k) {
        int o = tid + k * 256;
        int tok = o >> 6, e = o & 63;
        float s = 0.f;
#pragma unroll
        for (int d = 0; d < DH; ++d) s = fmaf(qfs[tok][d], kvs[d * DH + e], s);
        s /= denoms[tok];
        size_t idx = (size_t)(t0 + tok) * DMODEL + hh * DH + e;
        unsigned short hb = f2bf(s);
        out_hi[idx] = hb;
        out_lo[idx] = f2bf(s - bf2f(hb));
    }
}

extern "C" void kernel_launch(void* const* d_in, const int* in_sizes, int n_in,
                              void* d_out, int out_size, void* d_ws, size_t ws_size,
                              hipStream_t stream)
{
    const float* x  = (const float*)d_in[0];
    const float* wq = (const float*)d_in[1];
    const float* wk = (const float*)d_in[2];
    const float* wv = (const float*)d_in[3];
    const float* wo = (const float*)d_in[4];
    const float* bo = (const float*)d_in[5];
    float* out = (float*)d_out;

    const size_t XE = (size_t)TOK * DMODEL;       // 16 M elements
    const size_t WE = (size_t)DMODEL * DMODEL;    // 1 M elements
    const size_t CE = (size_t)8192 * DMODEL;      // 8 M (half-token chunk)

    // ws layout (~185 MiB, round-3-proven)
    unsigned short* xh = (unsigned short*)d_ws;            // 32 MiB
    unsigned short* xl = xh + XE;                           // 32 MiB
    unsigned short* wh = xl + XE;                           // 8 MiB (q,k,v,o)
    unsigned short* wl = wh + 4 * WE;                       // 8 MiB
    float* kf   = (float*)(wl + 4 * WE);                    // 64 MiB (reused as qf)
    float* vc   = kf + XE;                                  // 32 MiB (v chunk)
    float* kvp  = vc + CE;                                  // 8 MiB
    float* ksp  = kvp + (size_t)64 * KSPLIT * DH * DH;      // 128 KiB
    float* kvb  = ksp + (size_t)64 * KSPLIT * DH;           // 1 MiB
    float* ksmb = kvb + (size_t)64 * DH * DH;               // 16 KiB
    float* qf   = kf;                                       // alias: kf dead after kv

    // decompose inputs to bf16 hi/lo
    split_k<<<(int)(XE / 1024), 256, 0, stream>>>(x, xh, xl, (int)XE);
    splitw_k<<<4096, 256, 0, stream>>>(wq, wk, wv, wo, wh, wl);

    const int gfull = (TOK / 256) * 4;       // 256 blocks (1 per CU)
    const int ghalf = (8192 / 256) * 4;      // 128 blocks

    // k projection (full), then v projection + kv partials per 2-batch chunk
    gemm256_k<1><<<gfull, 512, 0, stream>>>(xh, xl, wh + WE, wl + WE, nullptr, kf, TOK, DMODEL, DMODEL);

    gemm256_k<0><<<ghalf, 512, 0, stream>>>(xh, xl, wh + 2 * WE, wl + 2 * WE, nullptr, vc, 8192, DMODEL, DMODEL);
    kv_partial_k<<<dim3(32, KSPLIT), 256, 0, stream>>>(kf, vc, 0, kvp, ksp);

    gemm256_k<0><<<ghalf, 512, 0, stream>>>(xh + CE, xl + CE, wh + 2 * WE, wl + 2 * WE, nullptr, vc, 8192, DMODEL, DMODEL);
    kv_partial_k<<<dim3(32, KSPLIT), 256, 0, stream>>>(kf, vc, 32, kvp, ksp);

    reduce_kv_k<<<dim3(64 * DH * DH / 256), 256, 0, stream>>>(kvp, ksp, kvb, ksmb);

    // q projection into kf's region (kf dead), then attn apply -> xh/xl
    gemm256_k<1><<<gfull, 512, 0, stream>>>(xh, xl, wh, wl, nullptr, qf, TOK, DMODEL, DMODEL);
    attn_out_k<<<dim3(TOK / 16, NHEAD), 256, 0, stream>>>(qf, kvb, ksmb, xh, xl);

    gemm256_k<2><<<gfull, 512, 0, stream>>>(xh, xl, wh + 3 * WE, wl + 3 * WE, bo, out, TOK, DMODEL, DMODEL);
}

// Round 6
// 518.313 us; speedup vs baseline: 3.3616x; 1.1286x over previous
//
#include <hip/hip_runtime.h>
#include <hip/hip_bf16.h>
#include <cmath>

// b=4, s=4096, d=1024, h=16, dh=64.  TOK = 16384.
// Split-bf16 (hi/lo) 16x16x32 MFMA for the four big GEMMs (256^2 dbuf tile)
// AND for the attn apply (q_kv with denom folded in as an extra B-row).

#define TOK    16384
#define DMODEL 1024
#define NHEAD  16
#define DH     64
#define KSPLIT 8

using bf16x8 = __attribute__((ext_vector_type(8))) short;
using f32x4  = __attribute__((ext_vector_type(4))) float;

typedef __attribute__((address_space(1))) const unsigned int gld_src_t;
typedef __attribute__((address_space(3))) unsigned int gld_dst_t;

__device__ __forceinline__ unsigned short f2bf(float x) {
    unsigned int u = __float_as_uint(x);
    u += 0x7fffu + ((u >> 16) & 1u);          // RNE
    return (unsigned short)(u >> 16);
}
__device__ __forceinline__ float bf2f(unsigned short b) {
    return __uint_as_float((unsigned int)b << 16);
}

// ---------------- split fp32 -> bf16 hi/lo ----------------
__global__ __launch_bounds__(256) void split_k(
    const float* __restrict__ in, unsigned short* __restrict__ hi,
    unsigned short* __restrict__ lo, int n)
{
    int i = (blockIdx.x * 256 + threadIdx.x) * 4;
    if (i >= n) return;
    float4 v = *(const float4*)(in + i);
    float vs[4] = {v.x, v.y, v.z, v.w};
    unsigned short hh[4], ll[4];
#pragma unroll
    for (int j = 0; j < 4; ++j) {
        unsigned short h = f2bf(vs[j]);
        hh[j] = h;
        ll[j] = f2bf(vs[j] - bf2f(h));
    }
    *(ushort4*)(hi + i) = make_ushort4(hh[0], hh[1], hh[2], hh[3]);
    *(ushort4*)(lo + i) = make_ushort4(ll[0], ll[1], ll[2], ll[3]);
}

// all four weight matrices in one dispatch (4096 blocks)
__global__ __launch_bounds__(256) void splitw_k(
    const float* __restrict__ w0, const float* __restrict__ w1,
    const float* __restrict__ w2, const float* __restrict__ w3,
    unsigned short* __restrict__ hs, unsigned short* __restrict__ ls)
{
    int w = blockIdx.x >> 10;
    const float* src = (w == 0) ? w0 : (w == 1) ? w1 : (w == 2) ? w2 : w3;
    int i = ((blockIdx.x & 1023) * 256 + threadIdx.x) * 4;
    size_t base = (size_t)w * (DMODEL * DMODEL);
    float4 v = *(const float4*)(src + i);
    float vs[4] = {v.x, v.y, v.z, v.w};
    unsigned short hh[4], ll[4];
#pragma unroll
    for (int j = 0; j < 4; ++j) {
        unsigned short h = f2bf(vs[j]);
        hh[j] = h;
        ll[j] = f2bf(vs[j] - bf2f(h));
    }
    *(ushort4*)(hs + base + i) = make_ushort4(hh[0], hh[1], hh[2], hh[3]);
    *(ushort4*)(ls + base + i) = make_ushort4(ll[0], ll[1], ll[2], ll[3]);
}

// ------- split-bf16 256x256 double-buffered GEMM: C[M,N] = A[M,K] @ B[N,K]^T -------
// ACT: 0 none, 1 elu+1 (fp32 out), 2 +bias (fp32 out), 3 elu+1 -> hi/lo bf16 out.
template<int ACT>
__global__ __launch_bounds__(512, 2) void gemm256_k(
    const unsigned short* __restrict__ Ah, const unsigned short* __restrict__ Al,
    const unsigned short* __restrict__ Bh, const unsigned short* __restrict__ Bl,
    const float* __restrict__ bias, float* __restrict__ C,
    unsigned short* __restrict__ Ch, unsigned short* __restrict__ Cl,
    int M, int N, int K)
{
    __shared__ unsigned short lds[2][4][256 * 32];   // [dbuf][Ah,Al,Bh,Bl][256r x 32k]
    const int tid  = threadIdx.x;
    const int lane = tid & 63, wid = tid >> 6;

    // XCD swizzle: 8 XCDs get contiguous m-panel chunks (nwg % 8 == 0)
    const int nwg = gridDim.x, cpx = nwg >> 3;
    const int g = ((int)blockIdx.x & 7) * cpx + ((int)blockIdx.x >> 3);
    const int m0 = (g >> 2) * 256, n0 = (g & 3) * 256;

    const int wr = wid >> 2, wc = wid & 3;       // wave tile: rows wr*128, cols wc*64
    const int fr = lane & 15, ko = lane >> 4;

    f32x4 acc[8][4];
#pragma unroll
    for (int i = 0; i < 8; ++i)
#pragma unroll
        for (int j = 0; j < 4; ++j) acc[i][j] = (f32x4){0.f, 0.f, 0.f, 0.f};

    // ---- staging: wave wid stages matrix (wid>>1), 128-row half (wid&1) ----
    const unsigned short* srcb = (wid < 2) ? Ah : (wid < 4) ? Al : (wid < 6) ? Bh : Bl;
    const int rowbase = ((wid < 4) ? m0 : n0) + (wid & 1) * 128;
    const int rloc = (wid & 1) * 128 + (lane >> 2);            // tile row at seg t=0
    const int sslot = (lane & 3) ^ ((rloc >> 1) & 3);          // t-invariant swizzle
    const unsigned short* gsrc0 = srcb + (size_t)(rowbase + (lane >> 2)) * K + sslot * 8;
    const int mat  = wid >> 1;
    const int ldso = ((wid & 1) * 128) * 32;                   // elem offset of half

    const int koff = (ko ^ ((fr >> 1) & 3)) * 8;
    const int nt = K / 32;

    // prologue: stage K-tile 0 into buf 0
#pragma unroll
    for (int t = 0; t < 8; ++t) {
        __builtin_amdgcn_global_load_lds((gld_src_t*)(gsrc0 + (size_t)t * 16 * K),
            (gld_dst_t*)&lds[0][mat][ldso + t * 512], 16, 0, 0);
    }
    __syncthreads();

    for (int t = 0; t < nt; ++t) {
        const int cur = t & 1;
        if (t + 1 < nt) {
            const unsigned short* gk = gsrc0 + (size_t)(t + 1) * 32;
#pragma unroll
            for (int u = 0; u < 8; ++u) {
                __builtin_amdgcn_global_load_lds((gld_src_t*)(gk + (size_t)u * 16 * K),
                    (gld_dst_t*)&lds[cur ^ 1][mat][ldso + u * 512], 16, 0, 0);
            }
        }
        bf16x8 ah[8], al[8];
#pragma unroll
        for (int mi = 0; mi < 8; ++mi) {
            int off = (wr * 128 + mi * 16 + fr) * 32 + koff;
            ah[mi] = *(const bf16x8*)&lds[cur][0][off];
            al[mi] = *(const bf16x8*)&lds[cur][1][off];
        }
#pragma unroll
        for (int nj = 0; nj < 4; ++nj) {
            int off = (wc * 64 + nj * 16 + fr) * 32 + koff;
            bf16x8 bh = *(const bf16x8*)&lds[cur][2][off];
            bf16x8 bl = *(const bf16x8*)&lds[cur][3][off];
#pragma unroll
            for (int mi = 0; mi < 8; ++mi) {
                acc[mi][nj] = __builtin_amdgcn_mfma_f32_16x16x32_bf16(ah[mi], bh, acc[mi][nj], 0, 0, 0);
                acc[mi][nj] = __builtin_amdgcn_mfma_f32_16x16x32_bf16(ah[mi], bl, acc[mi][nj], 0, 0, 0);
                acc[mi][nj] = __builtin_amdgcn_mfma_f32_16x16x32_bf16(al[mi], bh, acc[mi][nj], 0, 0, 0);
            }
        }
        __syncthreads();
    }

    // epilogue: C/D layout row=(lane>>4)*4+i, col=lane&15  [m89-verified]
    const int fq = ko;
#pragma unroll
    for (int mi = 0; mi < 8; ++mi) {
#pragma unroll
        for (int i = 0; i < 4; ++i) {
            int m = m0 + wr * 128 + mi * 16 + fq * 4 + i;
            size_t rbase = (size_t)m * N + n0 + wc * 64;
#pragma unroll
            for (int nj = 0; nj < 4; ++nj) {
                int n = nj * 16 + fr;
                float v = acc[mi][nj][i];
                if (ACT == 1 || ACT == 3) v = (v > 0.f) ? (v + 1.f) : expf(v);
                if (ACT == 2) v += bias[n0 + wc * 64 + n];
                if (ACT == 3) {
                    unsigned short hb = f2bf(v);
                    Ch[rbase + n] = hb;
                    Cl[rbase + n] = f2bf(v - bf2f(hb));
                } else {
                    C[rbase + n] = v;
                }
            }
        }
    }
}

// ------------- kv & k_sum partials for one 2-batch chunk -------------
__global__ __launch_bounds__(256) void kv_partial_k(
    const float* __restrict__ kf, const float* __restrict__ vchunk,
    int bh_base, float* __restrict__ kvp, float* __restrict__ ksp)
{
    __shared__ float kfs[8][64];
    __shared__ float vs[8][64];
    const int bh = bh_base + blockIdx.x;
    const int split = blockIdx.y;
    const int b = bh >> 4, h = bh & 15;
    const int blocal = b - (bh_base >> 4);
    const int tid = threadIdx.x;
    const int col = tid & 63, rg = tid >> 6;
    const int tx = tid & 15, ty = tid >> 4;
    const int di0 = ty * 4, dj0 = tx * 4;

    float acc[4][4] = {};
    float ks[4] = {0.f, 0.f, 0.f, 0.f};

    const int rows = 4096 / KSPLIT;
    const size_t kbase = ((size_t)b * 4096 + (size_t)split * rows) * DMODEL + h * DH;
    const size_t vbase = ((size_t)blocal * 4096 + (size_t)split * rows) * DMODEL + h * DH;

    for (int it = 0; it < rows / 8; ++it) {
        __syncthreads();
#pragma unroll
        for (int p = 0; p < 2; ++p) {
            int r = rg + p * 4;
            size_t o = (size_t)(it * 8 + r) * DMODEL + col;
            kfs[r][col] = kf[kbase + o];
            vs[r][col]  = vchunk[vbase + o];
        }
        __syncthreads();
#pragma unroll
        for (int r = 0; r < 8; ++r) {
            float a[4], bb[4];
#pragma unroll
            for (int i = 0; i < 4; ++i) a[i] = kfs[r][di0 + i];
#pragma unroll
            for (int j = 0; j < 4; ++j) bb[j] = vs[r][dj0 + j];
#pragma unroll
            for (int i = 0; i < 4; ++i)
#pragma unroll
                for (int j = 0; j < 4; ++j)
                    acc[i][j] = fmaf(a[i], bb[j], acc[i][j]);
            if (tx == 0) {
#pragma unroll
                for (int i = 0; i < 4; ++i) ks[i] += a[i];
            }
        }
    }

    const size_t obase = ((size_t)(bh * KSPLIT + split)) * (DH * DH);
#pragma unroll
    for (int i = 0; i < 4; ++i)
#pragma unroll
        for (int j = 0; j < 4; ++j)
            kvp[obase + (size_t)(di0 + i) * DH + dj0 + j] = acc[i][j];
    if (tx == 0) {
        size_t kb = ((size_t)(bh * KSPLIT + split)) * DH + di0;
#pragma unroll
        for (int i = 0; i < 4; ++i) ksp[kb + i] = ks[i];
    }
}

// ------------- reduce partials -> transposed hi/lo B-operand -------------
// kvt[bh][e][d] = kv[d][e] for e<64; kvt[bh][64][d] = ksum[d]; rows 65..95 unused.
__global__ __launch_bounds__(256) void reduce_kv_k(
    const float* __restrict__ kvp, const float* __restrict__ ksp,
    unsigned short* __restrict__ kvth, unsigned short* __restrict__ kvtl)
{
    int idx = blockIdx.x * 256 + threadIdx.x;     // 0..262143
    int bh = idx >> 12, off = idx & 4095;
    int d = off & 63, e = off >> 6;
    float s = 0.f;
    for (int c = 0; c < KSPLIT; ++c) s += kvp[((size_t)(bh * KSPLIT + c)) * 4096 + d * 64 + e];
    unsigned short hb = f2bf(s);
    size_t o = (size_t)bh * (96 * 64) + (size_t)e * 64 + d;
    kvth[o] = hb;
    kvtl[o] = f2bf(s - bf2f(hb));
    if (idx < 64 * DH) {
        int bh2 = idx >> 6, d2 = idx & 63;
        float t = 0.f;
        for (int c = 0; c < KSPLIT; ++c) t += ksp[((size_t)(bh2 * KSPLIT + c)) * DH + d2];
        unsigned short h2 = f2bf(t);
        size_t o2 = (size_t)bh2 * (96 * 64) + 64 * 64 + d2;
        kvth[o2] = h2;
        kvtl[o2] = f2bf(t - bf2f(h2));
    }
}

// ------------- attn apply via MFMA: attn = (qf @ kvt^T) / denom -------------
// Block: 128 tokens x 1 head, 8 waves (16 tok each), K=64 staged once.
// B rows 0..63 = kv^T, row 64 = ksum (-> output col 64 = denominator).
__global__ __launch_bounds__(512, 2) void attn_mfma_k(
    const unsigned short* __restrict__ qh, const unsigned short* __restrict__ ql,
    const unsigned short* __restrict__ kvth, const unsigned short* __restrict__ kvtl,
    unsigned short* __restrict__ out_hi, unsigned short* __restrict__ out_lo)
{
    __shared__ unsigned short lds[28672];   // Ah[128][64]@0, Al@8192, Bh[96][64]@16384, Bl@22528
    __shared__ float denoms[128];
    const int tid = threadIdx.x, lane = tid & 63, wid = tid >> 6;
    const int blk = blockIdx.x;             // 2048: bh*32 + tb
    const int bh = blk >> 5, tb = blk & 31;
    const int b = bh >> 4, h = bh & 15;
    const int t0 = b * 4096 + tb * 128;

    // ---- staging: 56 regions of 1 KiB (8 rows x 8 slots of 16B), 7 shots x 8 waves ----
    const int l8 = lane >> 3, s7 = lane & 7;
#pragma unroll
    for (int shot = 0; shot < 7; ++shot) {
        int r = wid * 7 + shot;
        const unsigned short* src;
        int dstE;
        if (r < 32) {                       // A: qf tile, rows = tokens
            int row = (r & 15) * 8 + l8;
            int sslot = s7 ^ (row & 7);
            src = ((r < 16) ? qh : ql) + (size_t)(t0 + row) * DMODEL + h * DH + sslot * 8;
            dstE = ((r < 16) ? 0 : 8192) + (r & 15) * 512;
        } else {                            // B: kvt tile, 96 rows
            int rb = r - 32;                // 0..23
            int rl = (rb < 12) ? rb : rb - 12;
            int row = rl * 8 + l8;
            int sslot = s7 ^ (row & 7);
            src = ((rb < 12) ? kvth : kvtl) + (size_t)bh * (96 * 64) + row * 64 + sslot * 8;
            dstE = ((rb < 12) ? 16384 : 22528) + rl * 512;
        }
        __builtin_amdgcn_global_load_lds((gld_src_t*)src, (gld_dst_t*)&lds[dstE], 16, 0, 0);
    }
    __syncthreads();

    const int fr = lane & 15, ko = lane >> 4, fq = ko;
    const int arow = wid * 16 + fr;         // token row within block

    f32x4 acc[5];
#pragma unroll
    for (int nj = 0; nj < 5; ++nj) acc[nj] = (f32x4){0.f, 0.f, 0.f, 0.f};

#pragma unroll
    for (int kt = 0; kt < 2; ++kt) {
        int aoff = arow * 64 + ((kt * 4 + ko) ^ (arow & 7)) * 8;
        bf16x8 a_h = *(const bf16x8*)&lds[aoff];
        bf16x8 a_l = *(const bf16x8*)&lds[8192 + aoff];
#pragma unroll
        for (int nj = 0; nj < 5; ++nj) {
            int brow = nj * 16 + fr;
            int boff = brow * 64 + ((kt * 4 + ko) ^ (brow & 7)) * 8;
            bf16x8 b_h = *(const bf16x8*)&lds[16384 + boff];
            bf16x8 b_l = *(const bf16x8*)&lds[22528 + boff];
            acc[nj] = __builtin_amdgcn_mfma_f32_16x16x32_bf16(a_h, b_h, acc[nj], 0, 0, 0);
            acc[nj] = __builtin_amdgcn_mfma_f32_16x16x32_bf16(a_h, b_l, acc[nj], 0, 0, 0);
            acc[nj] = __builtin_amdgcn_mfma_f32_16x16x32_bf16(a_l, b_h, acc[nj], 0, 0, 0);
        }
    }

    // denom lives in output col 64 (nj=4, fr==0)
    if (fr == 0) {
#pragma unroll
        for (int i = 0; i < 4; ++i)
            denoms[wid * 16 + fq * 4 + i] = acc[4][i] + 1e-6f;
    }
    __syncthreads();

#pragma unroll
    for (int i = 0; i < 4; ++i) {
        int row = wid * 16 + fq * 4 + i;    // token within block
        float dinv = 1.0f / denoms[row];
        size_t rbase = (size_t)(t0 + row) * DMODEL + h * DH;
#pragma unroll
        for (int nj = 0; nj < 4; ++nj) {
            float v = acc[nj][i] * dinv;
            unsigned short hb = f2bf(v);
            out_hi[rbase + nj * 16 + fr] = hb;
            out_lo[rbase + nj * 16 + fr] = f2bf(v - bf2f(hb));
        }
    }
}

extern "C" void kernel_launch(void* const* d_in, const int* in_sizes, int n_in,
                              void* d_out, int out_size, void* d_ws, size_t ws_size,
                              hipStream_t stream)
{
    const float* x  = (const float*)d_in[0];
    const float* wq = (const float*)d_in[1];
    const float* wk = (const float*)d_in[2];
    const float* wv = (const float*)d_in[3];
    const float* wo = (const float*)d_in[4];
    const float* bo = (const float*)d_in[5];
    float* out = (float*)d_out;

    const size_t XE = (size_t)TOK * DMODEL;       // 16 M elements
    const size_t WE = (size_t)DMODEL * DMODEL;    // 1 M elements
    const size_t CE = (size_t)8192 * DMODEL;      // 8 M (half-token chunk)

    // ws layout (~186 MiB)
    unsigned short* xh = (unsigned short*)d_ws;            // 32 MiB
    unsigned short* xl = xh + XE;                           // 32 MiB
    unsigned short* wh = xl + XE;                           // 8 MiB (q,k,v,o)
    unsigned short* wl = wh + 4 * WE;                       // 8 MiB
    float* kf   = (float*)(wl + 4 * WE);                    // 64 MiB (reused as qh/ql)
    float* vc   = kf + XE;                                  // 32 MiB (v chunk)
    float* kvp  = vc + CE;                                  // 8 MiB
    float* ksp  = kvp + (size_t)64 * KSPLIT * DH * DH;      // 128 KiB
    unsigned short* kvth = (unsigned short*)(ksp + (size_t)64 * KSPLIT * DH);  // 768 KiB
    unsigned short* kvtl = kvth + (size_t)64 * 96 * 64;                        // 768 KiB
    unsigned short* qh = (unsigned short*)kf;               // alias: kf dead after kv
    unsigned short* ql = qh + XE;

    // decompose inputs to bf16 hi/lo
    split_k<<<(int)(XE / 1024), 256, 0, stream>>>(x, xh, xl, (int)XE);
    splitw_k<<<4096, 256, 0, stream>>>(wq, wk, wv, wo, wh, wl);

    const int gfull = (TOK / 256) * 4;       // 256 blocks
    const int ghalf = (8192 / 256) * 4;      // 128 blocks

    // k projection (full fp32), then v projection + kv partials per 2-batch chunk
    gemm256_k<1><<<gfull, 512, 0, stream>>>(xh, xl, wh + WE, wl + WE, nullptr, kf, nullptr, nullptr, TOK, DMODEL, DMODEL);

    gemm256_k<0><<<ghalf, 512, 0, stream>>>(xh, xl, wh + 2 * WE, wl + 2 * WE, nullptr, vc, nullptr, nullptr, 8192, DMODEL, DMODEL);
    kv_partial_k<<<dim3(32, KSPLIT), 256, 0, stream>>>(kf, vc, 0, kvp, ksp);

    gemm256_k<0><<<ghalf, 512, 0, stream>>>(xh + CE, xl + CE, wh + 2 * WE, wl + 2 * WE, nullptr, vc, nullptr, nullptr, 8192, DMODEL, DMODEL);
    kv_partial_k<<<dim3(32, KSPLIT), 256, 0, stream>>>(kf, vc, 32, kvp, ksp);

    reduce_kv_k<<<dim3(64 * DH * DH / 256), 256, 0, stream>>>(kvp, ksp, kvth, kvtl);

    // q projection -> hi/lo bf16 into kf's region, then MFMA attn apply -> xh/xl
    gemm256_k<3><<<gfull, 512, 0, stream>>>(xh, xl, wh, wl, nullptr, nullptr, qh, ql, TOK, DMODEL, DMODEL);
    attn_mfma_k<<<2048, 512, 0, stream>>>(qh, ql, kvth, kvtl, xh, xl);

    gemm256_k<2><<<gfull, 512, 0, stream>>>(xh, xl, wh + 3 * WE, wl + 3 * WE, bo, out, nullptr, nullptr, TOK, DMODEL, DMODEL);
}